// Round 7
// baseline (1612.371 us; speedup 1.0000x reference)
//
#include <hip/hip_runtime.h>

// LSTMDiscriminator: B=256, T=1024, I=200, H=16
// K0: prepack W_ih (permuted cols, bf16, fragment-linear) + fused bias -> ws
// MEGA: blocks 0..255   = k2 role (LSTM scan, 1 wave, setprio(1), vmcnt self-sync)
//       blocks 256..16639 = k1 role (16-row MFMA xproj tile, tile-major, flags)
//       producer->consumer via per-(batch,chunk) atomic counters (release/acquire).
// K3: head relu(h@W1^T+b1)@W2^T+b2 -> sigmoid -> mean over T  (hst layout [b][j][t]).

#define T_LEN 1024
#define NB    256
#define CHUNK 128
#define NCH   (T_LEN / CHUNK)
#define NTILE 16384            // 64 tiles/batch * 256 batches
#define TILES_PER_CHUNK 8

#define F2I(x) __float_as_int(x)
#define I2F(x) __int_as_float(x)
#define DPPF(v, ctrl) I2F(__builtin_amdgcn_update_dpp(F2I(v), F2I(v), (ctrl), 0xF, 0xF, false))
// row_shl:4 (ctrl 0x104): lane i reads lane i+4 -> brings h_{j+1} to quad j
#define ROWSHL4(v) I2F(__builtin_amdgcn_update_dpp(F2I(v), F2I(v), 0x104, 0xF, 0xF, false))
#define RDLANE_I(v, l) __builtin_amdgcn_readlane((v), (l))

#define LOG2E 1.442695040888963f

typedef __bf16 bf16_t;
typedef bf16_t bf16x8 __attribute__((ext_vector_type(8)));
typedef float f32x4 __attribute__((ext_vector_type(4)));
typedef __fp16 half2_t __attribute__((ext_vector_type(2)));

#if __has_builtin(__builtin_amdgcn_exp2f)
__device__ __forceinline__ float fexp2(float x) { return __builtin_amdgcn_exp2f(x); }
#else
__device__ __forceinline__ float fexp2(float x) { return exp2f(x); }
#endif
#if __has_builtin(__builtin_amdgcn_rcpf)
__device__ __forceinline__ float frcp(float x) { return __builtin_amdgcn_rcpf(x); }
#else
__device__ __forceinline__ float frcp(float x) { return __fdividef(1.f, x); }
#endif

__device__ __forceinline__ half2_t i2h2(int x) { union { int i; half2_t h; } u; u.i = x; return u.h; }
__device__ __forceinline__ int h22i(half2_t h) { union { int i; half2_t h; } u; u.h = h; return u.i; }

#if __has_builtin(__builtin_amdgcn_fdot2)
#define FDOT2(a, b, c) __builtin_amdgcn_fdot2((a), (b), (c), false)
#else
__device__ __forceinline__ float FDOT2(half2_t a, half2_t b, float c) {
  return c + (float)a[0] * (float)b[0] + (float)a[1] * (float)b[1];
}
#endif

__device__ __forceinline__ float bf2f(unsigned short s) {
  return __uint_as_float(((unsigned int)s) << 16);
}
__device__ __forceinline__ unsigned int pkbf(float a, float b) {
  bf16_t x = (bf16_t)a, y = (bf16_t)b;
  unsigned short ux, uy;
  __builtin_memcpy(&ux, &x, 2); __builtin_memcpy(&uy, &y, 2);
  return (unsigned int)ux | ((unsigned int)uy << 16);
}

// ---------------- Kernel 0: prepack W (bf16, fragment-linear) + bias ----------------
__global__ __launch_bounds__(256) void k0_prep(
    const float* __restrict__ Wih, const float* __restrict__ bih,
    const float* __restrict__ bhh, bf16x8* __restrict__ wB,
    float* __restrict__ biasPerm)
{
  const int idx = blockIdx.x * 256 + threadIdx.x;   // 0..1791
  if (idx < 4 * 7 * 64) {
    const int f = idx / 448;
    const int rem = idx % 448;
    const int s = rem / 64;
    const int L = rem % 64;
    const int col = f * 16 + (L & 15);
    const int r = ((col & 3) << 4) | (col >> 2);
    const int k0 = s * 32 + (L >> 4) * 8;
    bf16x8 v;
#pragma unroll
    for (int e = 0; e < 8; ++e) {
      const int k = k0 + e;
      const float w = (k < 200) ? Wih[r * 200 + k] : 0.f;
      v[e] = (bf16_t)w;
    }
    wB[idx] = v;
  }
  if (blockIdx.x == 0 && threadIdx.x < 64) {
    const int c = threadIdx.x;
    const int r = ((c & 3) << 4) | (c >> 2);
    biasPerm[c] = bih[r] + bhh[r];
  }
}

// ---------------- helpers for mega kernel ----------------
__device__ __forceinline__ void stage_chunk(const unsigned short* g,
                                            unsigned short* l, int lane) {
#pragma unroll
  for (int it = 0; it < 16; ++it) {   // 16 x 1KB = 16KB (128 steps x 128B)
    __builtin_amdgcn_global_load_lds(
        (const __attribute__((address_space(1))) unsigned int*)(g + it * 512 + lane * 8),
        (__attribute__((address_space(3))) unsigned int*)(l + it * 512),
        16, 0, 0);
  }
}

__device__ __forceinline__ void waitflag(const unsigned int* p) {
  while (__hip_atomic_load(p, __ATOMIC_ACQUIRE, __HIP_MEMORY_SCOPE_AGENT)
         < TILES_PER_CHUNK)
    __builtin_amdgcn_s_sleep(1);
}

// pack h (quad-uniform) into 8 wave-uniform f16-pairs via DPP + cvt + readlane
#define PACKH(hval, d0,d1,d2,d3,d4,d5,d6,d7) do {            \
    float _hn = ROWSHL4(hval);                               \
    int _pk = h22i(__builtin_amdgcn_cvt_pkrtz((hval), _hn)); \
    d0 = RDLANE_I(_pk,  0); d1 = RDLANE_I(_pk,  8);          \
    d2 = RDLANE_I(_pk, 16); d3 = RDLANE_I(_pk, 24);          \
    d4 = RDLANE_I(_pk, 32); d5 = RDLANE_I(_pk, 40);          \
    d6 = RDLANE_I(_pk, 48); d7 = RDLANE_I(_pk, 56);          \
  } while (0)

// ---------------- MEGA kernel: k2 scan (blocks<NB) + k1 xproj (blocks>=NB) ----------------
__global__ __launch_bounds__(64) void mega(
    const float* __restrict__ x,
    const bf16x8* __restrict__ wB, const float* __restrict__ biasPerm,
    unsigned short* __restrict__ xproj,
    const float* __restrict__ h0, const float* __restrict__ c0,
    const float* __restrict__ Whh,
    unsigned short* __restrict__ hst,
    unsigned int* __restrict__ cnt)
{
  __shared__ unsigned short xs[2][CHUNK * 64];    // 2 x 16KB (reserved by both roles)

  if (blockIdx.x >= NB) {
    // ================= k1 role: one 16-row xproj tile =================
    const int idx  = blockIdx.x - NB;             // tile-major: early tiles first
    const int tile = idx >> 8;                    // 0..63
    const int bb   = idx & 255;
    const int L    = threadIdx.x;
    const int mrow = L & 15;
    const int kg   = L >> 4;                      // 0..3
    const long row0 = (long)bb * T_LEN + tile * 16;

    // A fragments straight from global (16 rows x 128B segments, coalesced)
    bf16x8 afr[7];
    const float* xr = x + (row0 + mrow) * 200;
#pragma unroll
    for (int s = 0; s < 7; ++s) {
      const int k0 = s * 32 + kg * 8;
      bf16x8 v;
      if (k0 <= 192) {
        float4 a  = *reinterpret_cast<const float4*>(xr + k0);
        float4 b4 = *reinterpret_cast<const float4*>(xr + k0 + 4);
        v[0] = (bf16_t)a.x;  v[1] = (bf16_t)a.y;  v[2] = (bf16_t)a.z;  v[3] = (bf16_t)a.w;
        v[4] = (bf16_t)b4.x; v[5] = (bf16_t)b4.y; v[6] = (bf16_t)b4.z; v[7] = (bf16_t)b4.w;
      } else {
        v[0] = (bf16_t)0.f; v[1] = (bf16_t)0.f; v[2] = (bf16_t)0.f; v[3] = (bf16_t)0.f;
        v[4] = (bf16_t)0.f; v[5] = (bf16_t)0.f; v[6] = (bf16_t)0.f; v[7] = (bf16_t)0.f;
      }
      afr[s] = v;
    }

    f32x4 acc0 = {0.f,0.f,0.f,0.f}, acc1 = {0.f,0.f,0.f,0.f};
    f32x4 acc2 = {0.f,0.f,0.f,0.f}, acc3 = {0.f,0.f,0.f,0.f};
#pragma unroll
    for (int s = 0; s < 7; ++s) {
      acc0 = __builtin_amdgcn_mfma_f32_16x16x32_bf16(afr[s], wB[(0*7+s)*64 + L], acc0, 0,0,0);
      acc1 = __builtin_amdgcn_mfma_f32_16x16x32_bf16(afr[s], wB[(1*7+s)*64 + L], acc1, 0,0,0);
      acc2 = __builtin_amdgcn_mfma_f32_16x16x32_bf16(afr[s], wB[(2*7+s)*64 + L], acc2, 0,0,0);
      acc3 = __builtin_amdgcn_mfma_f32_16x16x32_bf16(afr[s], wB[(3*7+s)*64 + L], acc3, 0,0,0);
    }

    // epilogue: (acc + bias) * colscale, store bf16 (C/D: col=lane&15, row=(lane>>4)*4+q)
    const int cb = L & 15;
    const float cs = ((cb & 3) == 2) ? (-2.f * LOG2E) : (-LOG2E);
    const long rbase = row0 + (kg << 2);
    __bf16* xo = (__bf16*)xproj;
    const float bv0 = biasPerm[ 0 + cb];
    const float bv1 = biasPerm[16 + cb];
    const float bv2 = biasPerm[32 + cb];
    const float bv3 = biasPerm[48 + cb];
#pragma unroll
    for (int q = 0; q < 4; ++q) {
      __bf16* row = xo + (rbase + q) * 64;
      row[ 0 + cb] = (bf16_t)((acc0[q] + bv0) * cs);
      row[16 + cb] = (bf16_t)((acc1[q] + bv1) * cs);
      row[32 + cb] = (bf16_t)((acc2[q] + bv2) * cs);
      row[48 + cb] = (bf16_t)((acc3[q] + bv3) * cs);
    }

    __threadfence();                              // drain + make stores visible
    if (L == 0)
      __hip_atomic_fetch_add(&cnt[bb * NCH + (tile >> 3)], 1u,
                             __ATOMIC_RELEASE, __HIP_MEMORY_SCOPE_AGENT);
    return;
  }

  // ================= k2 role: LSTM scan (single wave) =================
  __builtin_amdgcn_s_setprio(1);
  const int b = blockIdx.x;
  const int lane = threadIdx.x;
  const int g = lane & 3;
  const int j = lane >> 2;
  const int r = (g << 4) | j;

  const float sfac = (g == 2) ? (-2.f * LOG2E) : (-LOG2E);
  const float pfac = (g == 2) ?  2.f :  1.f;
  const float qfac = (g == 2) ? -1.f :  0.f;

  half2_t wpk[8];
#pragma unroll
  for (int q = 0; q < 4; ++q) {
    float4 w = *reinterpret_cast<const float4*>(Whh + r * 16 + q * 4);
    wpk[q * 2 + 0] = __builtin_amdgcn_cvt_pkrtz(w.x * sfac, w.y * sfac);
    wpk[q * 2 + 1] = __builtin_amdgcn_cvt_pkrtz(w.z * sfac, w.w * sfac);
  }

  float c = c0[b * 16 + j];
  float hmine = h0[b * 16 + j];                   // quad-uniform (j = lane>>2)
  int hp0, hp1, hp2, hp3, hp4, hp5, hp6, hp7;
  PACKH(hmine, hp0, hp1, hp2, hp3, hp4, hp5, hp6, hp7);

  unsigned short* hq = hst + (size_t)b * (16 * T_LEN) + j * T_LEN;  // [b][j][t]
  const unsigned short* gx = xproj + (size_t)b * (T_LEN * 64);
  const unsigned int* cw = cnt + b * NCH;

  waitflag(cw + 0);
  stage_chunk(gx, xs[0], lane);
  asm volatile("s_waitcnt vmcnt(0)" ::: "memory");

  float buf[8];
#pragma unroll
  for (int u = 0; u < 8; ++u)
    buf[u] = bf2f(xs[0][u * 64 + lane]);          // sfac folded in by producer

  for (int ch = 0; ch < NCH; ++ch) {
    if (ch + 1 < NCH) {
      waitflag(cw + ch + 1);
      stage_chunk(gx + (ch + 1) * (CHUNK * 64),
                  (unsigned short*)xs[(ch + 1) & 1], lane);
    }
    const unsigned short* xcur = xs[ch & 1];

    for (int ts = 0; ts < CHUNK; ts += 8) {
      const bool rel = (ts < CHUNK - 8);
      float hsv[8];
#pragma unroll
      for (int u = 0; u < 8; ++u) {
        const float gin = buf[u];
        if (rel) buf[u] = bf2f(xcur[(ts + 8 + u) * 64 + lane]);

        // pre' = sfac * (gin_raw + Whh h): 2 chains of 4 dot2 + combine
        float d0 = FDOT2(wpk[0], i2h2(hp0), gin);
        d0 = FDOT2(wpk[1], i2h2(hp1), d0);
        d0 = FDOT2(wpk[2], i2h2(hp2), d0);
        d0 = FDOT2(wpk[3], i2h2(hp3), d0);
        float d1 = FDOT2(wpk[4], i2h2(hp4), 0.f);
        d1 = FDOT2(wpk[5], i2h2(hp5), d1);
        d1 = FDOT2(wpk[6], i2h2(hp6), d1);
        d1 = FDOT2(wpk[7], i2h2(hp7), d1);
        float pre = d0 + d1;

        float e = fexp2(pre);
        float z = frcp(1.f + e);
        float y = fmaf(pfac, z, qfac);            // sigmoid or tanh

        float ai = DPPF(y, 0x00);
        float af = DPPF(y, 0x55);
        float ag = DPPF(y, 0xAA);
        float ao = DPPF(y, 0xFF);

        c = fmaf(af, c, ai * ag);
        float e2 = fexp2((2.f * LOG2E) * c);
        float th = fmaf(-2.f, frcp(1.f + e2), 1.f);
        float h = ao * th;                        // quad-uniform

        PACKH(h, hp0, hp1, hp2, hp3, hp4, hp5, hp6, hp7);
        hsv[u] = h;
      }
      if (g == 0) {                               // one 16B store per 8 steps
        uint4 pk;
        pk.x = pkbf(hsv[0], hsv[1]);
        pk.y = pkbf(hsv[2], hsv[3]);
        pk.z = pkbf(hsv[4], hsv[5]);
        pk.w = pkbf(hsv[6], hsv[7]);
        *reinterpret_cast<uint4*>(hq + ch * CHUNK + ts) = pk;
      }
    }

    asm volatile("s_waitcnt vmcnt(0)" ::: "memory");   // next chunk staged
    if (ch + 1 < NCH) {
      const unsigned short* xn = xs[(ch + 1) & 1];
#pragma unroll
      for (int u = 0; u < 8; ++u) buf[u] = bf2f(xn[u * 64 + lane]);
    }
  }
}

// ---------------- Kernel 3: head + mean (hst layout [b][j][t]) ----------------
__global__ __launch_bounds__(256) void k3_head(
    const unsigned short* __restrict__ hst,
    const float* __restrict__ W1, const float* __restrict__ b1,
    const float* __restrict__ W2, const float* __restrict__ b2,
    float* __restrict__ out)
{
  __shared__ float ws1[256];
  __shared__ float wsb1[16], wsw2[16];
  __shared__ float red[256];
  const int tid = threadIdx.x;
  const int b = blockIdx.x;

  ws1[tid] = W1[tid];
  if (tid < 16) { wsb1[tid] = b1[tid]; wsw2[tid] = W2[tid]; }
  __syncthreads();
  const float b2s = b2[0];

  const unsigned short* hb = hst + (size_t)b * (16 * T_LEN);
  float acc = 0.f;
#pragma unroll
  for (int it = 0; it < 2; ++it) {
    const int t2 = it * 256 + tid;               // pair index, t = 2*t2
    unsigned int hp[16];
#pragma unroll
    for (int jj = 0; jj < 16; ++jj)
      hp[jj] = *reinterpret_cast<const unsigned int*>(hb + jj * T_LEN + 2 * t2);
    float h0v[16], h1v[16];
#pragma unroll
    for (int k = 0; k < 16; ++k) {
      h0v[k] = bf2f((unsigned short)(hp[k] & 0xffff));
      h1v[k] = bf2f((unsigned short)(hp[k] >> 16));
    }
    float s0 = b2s, s1 = b2s;
#pragma unroll
    for (int jj = 0; jj < 16; ++jj) {
      float p0 = wsb1[jj], p1 = wsb1[jj];
#pragma unroll
      for (int k = 0; k < 16; ++k) {
        const float wv = ws1[jj * 16 + k];
        p0 = fmaf(wv, h0v[k], p0);
        p1 = fmaf(wv, h1v[k], p1);
      }
      p0 = fmaxf(p0, 0.f);
      p1 = fmaxf(p1, 0.f);
      s0 = fmaf(wsw2[jj], p0, s0);
      s1 = fmaf(wsw2[jj], p1, s1);
    }
    acc += frcp(1.f + fexp2(-LOG2E * s0));
    acc += frcp(1.f + fexp2(-LOG2E * s1));
  }

  red[tid] = acc;
  __syncthreads();
  if (tid < 128) red[tid] += red[tid + 128];
  __syncthreads();
  if (tid < 64) {
    float v = red[tid] + red[tid + 64];
    v += __shfl_xor(v, 32, 64);
    v += __shfl_xor(v, 16, 64);
    v += __shfl_xor(v, 8, 64);
    v += __shfl_xor(v, 4, 64);
    v += __shfl_xor(v, 2, 64);
    v += __shfl_xor(v, 1, 64);
    if (tid == 0) out[b] = v * (1.f / T_LEN);
  }
}

// ---------------- launcher ----------------
extern "C" void kernel_launch(void* const* d_in, const int* in_sizes, int n_in,
                              void* d_out, int out_size, void* d_ws, size_t ws_size,
                              hipStream_t stream) {
  const float* x   = (const float*)d_in[0];
  const float* h0  = (const float*)d_in[1];
  const float* c0  = (const float*)d_in[2];
  const float* Wih = (const float*)d_in[3];
  const float* Whh = (const float*)d_in[4];
  const float* bih = (const float*)d_in[5];
  const float* bhh = (const float*)d_in[6];
  const float* W1  = (const float*)d_in[7];
  const float* b1  = (const float*)d_in[8];
  const float* W2  = (const float*)d_in[9];
  const float* b2  = (const float*)d_in[10];

  char* wsb = (char*)d_ws;
  unsigned short* xproj = (unsigned short*)wsb;                     // 32 MiB
  unsigned short* hst   = (unsigned short*)(wsb + 33554432);        // 8 MiB
  bf16x8* wB            = (bf16x8*)(wsb + 41943040);                // 28 KiB
  float* biasPerm       = (float*)(wsb + 41943040 + 32768);         // 256 B
  unsigned int* cnt     = (unsigned int*)(wsb + 41943040 + 65536);  // 8 KiB

  hipMemsetAsync(cnt, 0, NB * NCH * sizeof(unsigned int), stream);
  hipLaunchKernelGGL(k0_prep, dim3(7), dim3(256), 0, stream,
                     Wih, bih, bhh, wB, biasPerm);
  hipLaunchKernelGGL(mega, dim3(NB + NTILE), dim3(64), 0, stream,
                     x, wB, biasPerm, xproj, h0, c0, Whh, hst, cnt);
  hipLaunchKernelGGL(k3_head, dim3(NB), dim3(256), 0, stream,
                     hst, W1, b1, W2, b2, (float*)d_out);
}

// Round 8
// 160.669 us; speedup vs baseline: 10.0354x; 10.0354x over previous
//
#include <hip/hip_runtime.h>

// LSTMDiscriminator: B=256, T=1024, I=200, H=16
// K0: prepack W_ih (permuted cols, bf16, fragment-linear) with the gate exp2
//     scale (sfac) folded in; bias folded+scaled -> biasPerm.
// MEGA: one block per batch (256 threads = 4 waves).
//       wave 0   = LSTM scanner (reads f32 gate preacts from LDS)
//       waves1-3 = MFMA producers: x_proj chunk -> LDS double buffer
//       sync: LDS workgroup-scope atomics only (no cross-XCD traffic).
// K3: head relu(h@W1^T+b1)@W2^T+b2 -> sigmoid -> mean over T (hst [b][j][t]).

#define T_LEN 1024
#define NB    256
#define CHUNK 128
#define NCH   (T_LEN / CHUNK)

#define F2I(x) __float_as_int(x)
#define I2F(x) __int_as_float(x)
#define DPPF(v, ctrl) I2F(__builtin_amdgcn_update_dpp(F2I(v), F2I(v), (ctrl), 0xF, 0xF, false))
#define ROWSHL4(v) I2F(__builtin_amdgcn_update_dpp(F2I(v), F2I(v), 0x104, 0xF, 0xF, false))
#define RDLANE_I(v, l) __builtin_amdgcn_readlane((v), (l))

#define LOG2E 1.442695040888963f

typedef __bf16 bf16_t;
typedef bf16_t bf16x8 __attribute__((ext_vector_type(8)));
typedef float f32x4 __attribute__((ext_vector_type(4)));
typedef __fp16 half2_t __attribute__((ext_vector_type(2)));

#if __has_builtin(__builtin_amdgcn_exp2f)
__device__ __forceinline__ float fexp2(float x) { return __builtin_amdgcn_exp2f(x); }
#else
__device__ __forceinline__ float fexp2(float x) { return exp2f(x); }
#endif
#if __has_builtin(__builtin_amdgcn_rcpf)
__device__ __forceinline__ float frcp(float x) { return __builtin_amdgcn_rcpf(x); }
#else
__device__ __forceinline__ float frcp(float x) { return __fdividef(1.f, x); }
#endif

__device__ __forceinline__ half2_t i2h2(int x) { union { int i; half2_t h; } u; u.i = x; return u.h; }
__device__ __forceinline__ int h22i(half2_t h) { union { int i; half2_t h; } u; u.h = h; return u.i; }

#if __has_builtin(__builtin_amdgcn_fdot2)
#define FDOT2(a, b, c) __builtin_amdgcn_fdot2((a), (b), (c), false)
#else
__device__ __forceinline__ float FDOT2(half2_t a, half2_t b, float c) {
  return c + (float)a[0] * (float)b[0] + (float)a[1] * (float)b[1];
}
#endif

__device__ __forceinline__ float bf2f(unsigned short s) {
  return __uint_as_float(((unsigned int)s) << 16);
}
__device__ __forceinline__ unsigned int pkbf(float a, float b) {
  bf16_t x = (bf16_t)a, y = (bf16_t)b;
  unsigned short ux, uy;
  __builtin_memcpy(&ux, &x, 2); __builtin_memcpy(&uy, &y, 2);
  return (unsigned int)ux | ((unsigned int)uy << 16);
}

// ---------------- Kernel 0: prepack W (bf16, fragment-linear, sfac folded) ----------------
// chunk idx = (f*7 + s)*64 + L holds sfac(col) * W[k = s*32+(L>>4)*8+e][col = f*16+(L&15)]
__global__ __launch_bounds__(256) void k0_prep(
    const float* __restrict__ Wih, const float* __restrict__ bih,
    const float* __restrict__ bhh, bf16x8* __restrict__ wB,
    float* __restrict__ biasPerm)
{
  const int idx = blockIdx.x * 256 + threadIdx.x;   // 0..1791
  if (idx < 4 * 7 * 64) {
    const int f = idx / 448;
    const int rem = idx % 448;
    const int s = rem / 64;
    const int L = rem % 64;
    const int col = f * 16 + (L & 15);
    const int r = ((col & 3) << 4) | (col >> 2);
    const float sf = ((col & 3) == 2) ? (-2.f * LOG2E) : (-LOG2E);
    const int k0 = s * 32 + (L >> 4) * 8;
    bf16x8 v;
#pragma unroll
    for (int e = 0; e < 8; ++e) {
      const int k = k0 + e;
      const float w = (k < 200) ? (Wih[r * 200 + k] * sf) : 0.f;
      v[e] = (bf16_t)w;
    }
    wB[idx] = v;
  }
  if (blockIdx.x == 0 && threadIdx.x < 64) {
    const int c = threadIdx.x;
    const int r = ((c & 3) << 4) | (c >> 2);
    const float sf = ((c & 3) == 2) ? (-2.f * LOG2E) : (-LOG2E);
    biasPerm[c] = (bih[r] + bhh[r]) * sf;
  }
}

// pack h (quad-uniform) into 8 wave-uniform f16-pairs
#define PACKH(hval, d0,d1,d2,d3,d4,d5,d6,d7) do {            \
    float _hn = ROWSHL4(hval);                               \
    int _pk = h22i(__builtin_amdgcn_cvt_pkrtz((hval), _hn)); \
    d0 = RDLANE_I(_pk,  0); d1 = RDLANE_I(_pk,  8);          \
    d2 = RDLANE_I(_pk, 16); d3 = RDLANE_I(_pk, 24);          \
    d4 = RDLANE_I(_pk, 32); d5 = RDLANE_I(_pk, 40);          \
    d6 = RDLANE_I(_pk, 48); d7 = RDLANE_I(_pk, 56);          \
  } while (0)

// ---------------- MEGA kernel: per-batch producer/consumer in one block ----------------
__global__ __launch_bounds__(256, 1) void mega(
    const float* __restrict__ x,
    const bf16x8* __restrict__ wB, const float* __restrict__ biasPerm,
    const float* __restrict__ h0, const float* __restrict__ c0,
    const float* __restrict__ Whh,
    unsigned short* __restrict__ hst)
{
  __shared__ float xsf[2][CHUNK * 64];   // 2 x 32KB, f32 gate preacts
  __shared__ int flags[NCH];             // tiles completed per chunk (8 = ready)
  __shared__ int doneCnt;                // chunks fully consumed by scanner

  const int tid  = threadIdx.x;
  const int lane = tid & 63;
  const int wid  = tid >> 6;
  const int b    = blockIdx.x;

  if (tid < NCH) flags[tid] = 0;
  if (tid == NCH) doneCnt = 0;
  __syncthreads();                       // single uniform barrier, then roles split

  if (wid != 0) {
    // ================= producer waves (1..3): x_proj tiles -> LDS =================
    const int pw   = wid - 1;            // 0..2
    const int L    = lane;
    const int mrow = L & 15;
    const int kg   = L >> 4;             // 0..3
    const int cb   = L & 15;

    bf16x8 Bv[28];                       // all B-fragments resident in VGPRs
#pragma unroll
    for (int i = 0; i < 28; ++i) Bv[i] = wB[i * 64 + L];
    const float bv0 = biasPerm[ 0 + cb];
    const float bv1 = biasPerm[16 + cb];
    const float bv2 = biasPerm[32 + cb];
    const float bv3 = biasPerm[48 + cb];

    for (int t = pw; t < 64; t += 3) {   // 16-row tiles, chunk = t>>3
      const int ch = t >> 3;
      if (ch >= 2) {
        while (__hip_atomic_load(&doneCnt, __ATOMIC_ACQUIRE,
                                 __HIP_MEMORY_SCOPE_WORKGROUP) < ch - 1)
          __builtin_amdgcn_s_sleep(2);
      }

      const float* xr = x + ((size_t)b * T_LEN + t * 16 + mrow) * 200;
      bf16x8 afr[7];
#pragma unroll
      for (int s = 0; s < 7; ++s) {
        const int k0 = s * 32 + kg * 8;
        bf16x8 v;
        if (k0 <= 192) {
          float4 a  = *reinterpret_cast<const float4*>(xr + k0);
          float4 b4 = *reinterpret_cast<const float4*>(xr + k0 + 4);
          v[0] = (bf16_t)a.x;  v[1] = (bf16_t)a.y;  v[2] = (bf16_t)a.z;  v[3] = (bf16_t)a.w;
          v[4] = (bf16_t)b4.x; v[5] = (bf16_t)b4.y; v[6] = (bf16_t)b4.z; v[7] = (bf16_t)b4.w;
        } else {
          v[0] = (bf16_t)0.f; v[1] = (bf16_t)0.f; v[2] = (bf16_t)0.f; v[3] = (bf16_t)0.f;
          v[4] = (bf16_t)0.f; v[5] = (bf16_t)0.f; v[6] = (bf16_t)0.f; v[7] = (bf16_t)0.f;
        }
        afr[s] = v;
      }

      f32x4 acc0 = {0.f,0.f,0.f,0.f}, acc1 = {0.f,0.f,0.f,0.f};
      f32x4 acc2 = {0.f,0.f,0.f,0.f}, acc3 = {0.f,0.f,0.f,0.f};
#pragma unroll
      for (int s = 0; s < 7; ++s) {
        acc0 = __builtin_amdgcn_mfma_f32_16x16x32_bf16(afr[s], Bv[0*7+s], acc0, 0,0,0);
        acc1 = __builtin_amdgcn_mfma_f32_16x16x32_bf16(afr[s], Bv[1*7+s], acc1, 0,0,0);
        acc2 = __builtin_amdgcn_mfma_f32_16x16x32_bf16(afr[s], Bv[2*7+s], acc2, 0,0,0);
        acc3 = __builtin_amdgcn_mfma_f32_16x16x32_bf16(afr[s], Bv[3*7+s], acc3, 0,0,0);
      }

      // C/D: col = lane&15, row = (lane>>4)*4 + q. Write f32 preacts (scaled+biased).
      float* dst = xsf[ch & 1] + ((t & 7) * 16) * 64;
#pragma unroll
      for (int q = 0; q < 4; ++q) {
        float* rowp = dst + (kg * 4 + q) * 64;
        rowp[ 0 + cb] = acc0[q] + bv0;
        rowp[16 + cb] = acc1[q] + bv1;
        rowp[32 + cb] = acc2[q] + bv2;
        rowp[48 + cb] = acc3[q] + bv3;
      }
      asm volatile("s_waitcnt lgkmcnt(0)" ::: "memory");
      __hip_atomic_fetch_add(&flags[ch], 1, __ATOMIC_RELEASE,
                             __HIP_MEMORY_SCOPE_WORKGROUP);
    }
    return;
  }

  // ================= scanner wave (wave 0): LSTM over 1024 steps =================
  __builtin_amdgcn_s_setprio(1);
  const int g = lane & 3;
  const int j = lane >> 2;
  const int r = (g << 4) | j;

  const float sfac = (g == 2) ? (-2.f * LOG2E) : (-LOG2E);
  // pfac: i-gate pre-scaled by 2*log2e so c stays in exp2 domain; g-gate tanh.
  const float pfac = (g == 0) ? (2.f * LOG2E) : ((g == 2) ? 2.f : 1.f);
  const float qfac = (g == 2) ? -1.f : 0.f;

  half2_t wpk[8];
#pragma unroll
  for (int q = 0; q < 4; ++q) {
    float4 w = *reinterpret_cast<const float4*>(Whh + r * 16 + q * 4);
    wpk[q * 2 + 0] = __builtin_amdgcn_cvt_pkrtz(w.x * sfac, w.y * sfac);
    wpk[q * 2 + 1] = __builtin_amdgcn_cvt_pkrtz(w.z * sfac, w.w * sfac);
  }

  float c = c0[b * 16 + j] * (2.f * LOG2E);       // scaled cell state
  float hmine = h0[b * 16 + j];                   // quad-uniform
  int hp0, hp1, hp2, hp3, hp4, hp5, hp6, hp7;
  PACKH(hmine, hp0, hp1, hp2, hp3, hp4, hp5, hp6, hp7);

  unsigned short* hq = hst + (size_t)b * (16 * T_LEN) + j * T_LEN;  // [b][j][t]

  for (int ch = 0; ch < NCH; ++ch) {
    while (__hip_atomic_load(&flags[ch], __ATOMIC_ACQUIRE,
                             __HIP_MEMORY_SCOPE_WORKGROUP) < 8)
      __builtin_amdgcn_s_sleep(1);

    const float* xc = xsf[ch & 1];
    float buf[8];
#pragma unroll
    for (int u = 0; u < 8; ++u) buf[u] = xc[u * 64 + lane];

    for (int ts = 0; ts < CHUNK; ts += 8) {
      float hsv[8];
#pragma unroll
      for (int u = 0; u < 8; ++u) {
        const float gin = buf[u];                 // sfac*(Wx+b), f32
        if (ts < CHUNK - 8) buf[u] = xc[(ts + 8 + u) * 64 + lane];

        // pre = sfac*(gin_raw + Whh h): 2 chains of 4 dot2 + combine
        float d0 = FDOT2(wpk[0], i2h2(hp0), gin);
        d0 = FDOT2(wpk[1], i2h2(hp1), d0);
        d0 = FDOT2(wpk[2], i2h2(hp2), d0);
        d0 = FDOT2(wpk[3], i2h2(hp3), d0);
        float d1 = FDOT2(wpk[4], i2h2(hp4), 0.f);
        d1 = FDOT2(wpk[5], i2h2(hp5), d1);
        d1 = FDOT2(wpk[6], i2h2(hp6), d1);
        d1 = FDOT2(wpk[7], i2h2(hp7), d1);
        float pre = d0 + d1;

        float e = fexp2(pre);
        float z = frcp(1.f + e);
        float y = fmaf(pfac, z, qfac);  // g0: 2log2e*i, g1: f, g2: tanh g, g3: o

        // c' = f*c' + (2log2e*i)*g  via quad DPP combine
        float t1 = DPPF(y, 0x4E) * y;             // lane0: (2log2e*i)*g
        float ig = DPPF(t1, 0x00);                // broadcast to quad
        c = fmaf(DPPF(y, 0x55), c, ig);           // f from lane1

        float e2 = fexp2(c);                      // e^{2c_true}
        float z2 = frcp(1.f + e2);
        float th = fmaf(-2.f, z2, 1.f);           // tanh(c_true)
        float h = DPPF(y, 0xFF) * th;             // o from lane3; quad-uniform

        PACKH(h, hp0, hp1, hp2, hp3, hp4, hp5, hp6, hp7);
        hsv[u] = h;
      }
      if (g == 0) {                               // one 16B store per 8 steps
        uint4 pk;
        pk.x = pkbf(hsv[0], hsv[1]);
        pk.y = pkbf(hsv[2], hsv[3]);
        pk.z = pkbf(hsv[4], hsv[5]);
        pk.w = pkbf(hsv[6], hsv[7]);
        *reinterpret_cast<uint4*>(hq + ch * CHUNK + ts) = pk;
      }
    }

    __hip_atomic_store(&doneCnt, ch + 1, __ATOMIC_RELEASE,
                       __HIP_MEMORY_SCOPE_WORKGROUP);
  }
}

// ---------------- Kernel 3: head + mean (hst layout [b][j][t]) ----------------
__global__ __launch_bounds__(256) void k3_head(
    const unsigned short* __restrict__ hst,
    const float* __restrict__ W1, const float* __restrict__ b1,
    const float* __restrict__ W2, const float* __restrict__ b2,
    float* __restrict__ out)
{
  __shared__ float ws1[256];
  __shared__ float wsb1[16], wsw2[16];
  __shared__ float red[256];
  const int tid = threadIdx.x;
  const int b = blockIdx.x;

  ws1[tid] = W1[tid];
  if (tid < 16) { wsb1[tid] = b1[tid]; wsw2[tid] = W2[tid]; }
  __syncthreads();
  const float b2s = b2[0];

  const unsigned short* hb = hst + (size_t)b * (16 * T_LEN);
  float acc = 0.f;
#pragma unroll
  for (int it = 0; it < 2; ++it) {
    const int t2 = it * 256 + tid;               // pair index, t = 2*t2
    unsigned int hp[16];
#pragma unroll
    for (int jj = 0; jj < 16; ++jj)
      hp[jj] = *reinterpret_cast<const unsigned int*>(hb + jj * T_LEN + 2 * t2);
    float h0v[16], h1v[16];
#pragma unroll
    for (int k = 0; k < 16; ++k) {
      h0v[k] = bf2f((unsigned short)(hp[k] & 0xffff));
      h1v[k] = bf2f((unsigned short)(hp[k] >> 16));
    }
    float s0 = b2s, s1 = b2s;
#pragma unroll
    for (int jj = 0; jj < 16; ++jj) {
      float p0 = wsb1[jj], p1 = wsb1[jj];
#pragma unroll
      for (int k = 0; k < 16; ++k) {
        const float wv = ws1[jj * 16 + k];
        p0 = fmaf(wv, h0v[k], p0);
        p1 = fmaf(wv, h1v[k], p1);
      }
      p0 = fmaxf(p0, 0.f);
      p1 = fmaxf(p1, 0.f);
      s0 = fmaf(wsw2[jj], p0, s0);
      s1 = fmaf(wsw2[jj], p1, s1);
    }
    acc += frcp(1.f + fexp2(-LOG2E * s0));
    acc += frcp(1.f + fexp2(-LOG2E * s1));
  }

  red[tid] = acc;
  __syncthreads();
  if (tid < 128) red[tid] += red[tid + 128];
  __syncthreads();
  if (tid < 64) {
    float v = red[tid] + red[tid + 64];
    v += __shfl_xor(v, 32, 64);
    v += __shfl_xor(v, 16, 64);
    v += __shfl_xor(v, 8, 64);
    v += __shfl_xor(v, 4, 64);
    v += __shfl_xor(v, 2, 64);
    v += __shfl_xor(v, 1, 64);
    if (tid == 0) out[b] = v * (1.f / T_LEN);
  }
}

// ---------------- launcher ----------------
extern "C" void kernel_launch(void* const* d_in, const int* in_sizes, int n_in,
                              void* d_out, int out_size, void* d_ws, size_t ws_size,
                              hipStream_t stream) {
  const float* x   = (const float*)d_in[0];
  const float* h0  = (const float*)d_in[1];
  const float* c0  = (const float*)d_in[2];
  const float* Wih = (const float*)d_in[3];
  const float* Whh = (const float*)d_in[4];
  const float* bih = (const float*)d_in[5];
  const float* bhh = (const float*)d_in[6];
  const float* W1  = (const float*)d_in[7];
  const float* b1  = (const float*)d_in[8];
  const float* W2  = (const float*)d_in[9];
  const float* b2  = (const float*)d_in[10];

  char* wsb = (char*)d_ws;
  unsigned short* hst = (unsigned short*)wsb;                 // 8 MiB
  bf16x8* wB          = (bf16x8*)(wsb + 8388608);             // 28 KiB
  float* biasPerm     = (float*)(wsb + 8388608 + 32768);      // 256 B

  hipLaunchKernelGGL(k0_prep, dim3(7), dim3(256), 0, stream,
                     Wih, bih, bhh, wB, biasPerm);
  hipLaunchKernelGGL(mega, dim3(NB), dim3(256), 0, stream,
                     x, wB, biasPerm, h0, c0, Whh, hst);
  hipLaunchKernelGGL(k3_head, dim3(NB), dim3(256), 0, stream,
                     hst, W1, b1, W2, b2, (float*)d_out);
}

// Round 9
// 159.063 us; speedup vs baseline: 10.1367x; 1.0101x over previous
//
#include <hip/hip_runtime.h>

// LSTMDiscriminator: B=256, T=1024, I=200, H=16
// K0: prepack W_ih (permuted cols, bf16, fragment-linear) with gate exp2 scale
//     folded; bias folded+scaled -> biasPerm.
// MEGA: one block per batch (256 threads = 4 waves).
//       wave 0   = LSTM scanner (f32 gate preacts from LDS)
//       waves1-3 = MFMA producers -> LDS double buffer (stride-68 rows)
//       sync: barrier-phased pipeline (9 x s_barrier), NO atomics/polling.
// K3: head relu(h@W1^T+b1)@W2^T+b2 -> sigmoid -> mean over T (hst [b][j][t]).

#define T_LEN 1024
#define NB    256
#define CHUNK 128
#define NCH   (T_LEN / CHUNK)
#define XSTR  68               // LDS row stride in floats (bank-conflict-free)

#define F2I(x) __float_as_int(x)
#define I2F(x) __int_as_float(x)
#define DPPF(v, ctrl) I2F(__builtin_amdgcn_update_dpp(F2I(v), F2I(v), (ctrl), 0xF, 0xF, false))
#define ROWSHL4(v) I2F(__builtin_amdgcn_update_dpp(F2I(v), F2I(v), 0x104, 0xF, 0xF, false))
#define RDLANE_I(v, l) __builtin_amdgcn_readlane((v), (l))

#define LOG2E 1.442695040888963f

typedef __bf16 bf16_t;
typedef bf16_t bf16x8 __attribute__((ext_vector_type(8)));
typedef float f32x4 __attribute__((ext_vector_type(4)));
typedef __fp16 half2_t __attribute__((ext_vector_type(2)));

#if __has_builtin(__builtin_amdgcn_exp2f)
__device__ __forceinline__ float fexp2(float x) { return __builtin_amdgcn_exp2f(x); }
#else
__device__ __forceinline__ float fexp2(float x) { return exp2f(x); }
#endif
#if __has_builtin(__builtin_amdgcn_rcpf)
__device__ __forceinline__ float frcp(float x) { return __builtin_amdgcn_rcpf(x); }
#else
__device__ __forceinline__ float frcp(float x) { return __fdividef(1.f, x); }
#endif

__device__ __forceinline__ half2_t i2h2(int x) { union { int i; half2_t h; } u; u.i = x; return u.h; }
__device__ __forceinline__ int h22i(half2_t h) { union { int i; half2_t h; } u; u.h = h; return u.i; }

#if __has_builtin(__builtin_amdgcn_fdot2)
#define FDOT2(a, b, c) __builtin_amdgcn_fdot2((a), (b), (c), false)
#else
__device__ __forceinline__ float FDOT2(half2_t a, half2_t b, float c) {
  return c + (float)a[0] * (float)b[0] + (float)a[1] * (float)b[1];
}
#endif

__device__ __forceinline__ float bf2f(unsigned short s) {
  return __uint_as_float(((unsigned int)s) << 16);
}
__device__ __forceinline__ unsigned int pkbf(float a, float b) {
  bf16_t x = (bf16_t)a, y = (bf16_t)b;
  unsigned short ux, uy;
  __builtin_memcpy(&ux, &x, 2); __builtin_memcpy(&uy, &y, 2);
  return (unsigned int)ux | ((unsigned int)uy << 16);
}

// ---------------- Kernel 0: prepack W (bf16, fragment-linear, sfac folded) ----------------
__global__ __launch_bounds__(256) void k0_prep(
    const float* __restrict__ Wih, const float* __restrict__ bih,
    const float* __restrict__ bhh, bf16x8* __restrict__ wB,
    float* __restrict__ biasPerm)
{
  const int idx = blockIdx.x * 256 + threadIdx.x;   // 0..1791
  if (idx < 4 * 7 * 64) {
    const int f = idx / 448;
    const int rem = idx % 448;
    const int s = rem / 64;
    const int L = rem % 64;
    const int col = f * 16 + (L & 15);
    const int r = ((col & 3) << 4) | (col >> 2);
    const float sf = ((col & 3) == 2) ? (-2.f * LOG2E) : (-LOG2E);
    const int k0 = s * 32 + (L >> 4) * 8;
    bf16x8 v;
#pragma unroll
    for (int e = 0; e < 8; ++e) {
      const int k = k0 + e;
      const float w = (k < 200) ? (Wih[r * 200 + k] * sf) : 0.f;
      v[e] = (bf16_t)w;
    }
    wB[idx] = v;
  }
  if (blockIdx.x == 0 && threadIdx.x < 64) {
    const int c = threadIdx.x;
    const int r = ((c & 3) << 4) | (c >> 2);
    const float sf = ((c & 3) == 2) ? (-2.f * LOG2E) : (-LOG2E);
    biasPerm[c] = (bih[r] + bhh[r]) * sf;
  }
}

// pack h (quad-uniform) into 8 wave-uniform f16-pairs
#define PACKH(hval, d0,d1,d2,d3,d4,d5,d6,d7) do {            \
    float _hn = ROWSHL4(hval);                               \
    int _pk = h22i(__builtin_amdgcn_cvt_pkrtz((hval), _hn)); \
    d0 = RDLANE_I(_pk,  0); d1 = RDLANE_I(_pk,  8);          \
    d2 = RDLANE_I(_pk, 16); d3 = RDLANE_I(_pk, 24);          \
    d4 = RDLANE_I(_pk, 32); d5 = RDLANE_I(_pk, 40);          \
    d6 = RDLANE_I(_pk, 48); d7 = RDLANE_I(_pk, 56);          \
  } while (0)

// ---------------- MEGA kernel: barrier-phased producer/consumer per batch ----------------
__global__ __launch_bounds__(256, 1) void mega(
    const float* __restrict__ x,
    const bf16x8* __restrict__ wB, const float* __restrict__ biasPerm,
    const float* __restrict__ h0, const float* __restrict__ c0,
    const float* __restrict__ Whh,
    unsigned short* __restrict__ hst)
{
  __shared__ float xsf[2][CHUNK * XSTR];   // 2 x 34816 B, f32 gate preacts

  const int tid  = threadIdx.x;
  const int lane = tid & 63;
  const int wid  = tid >> 6;
  const int b    = blockIdx.x;

  if (wid != 0) {
    // ================= producer waves (1..3) =================
    const int pw   = wid - 1;            // 0..2
    const int L    = lane;
    const int mrow = L & 15;
    const int kg   = L >> 4;             // 0..3
    const int cb   = L & 15;

    bf16x8 Bv[28];                       // all B-fragments resident in VGPRs
#pragma unroll
    for (int i = 0; i < 28; ++i) Bv[i] = wB[i * 64 + L];
    const float bv0 = biasPerm[ 0 + cb];
    const float bv1 = biasPerm[16 + cb];
    const float bv2 = biasPerm[32 + cb];
    const float bv3 = biasPerm[48 + cb];

    // produce chunk `pc` into xsf[pc & 1]
    auto produce = [&](int pc) {
      for (int t8 = pw; t8 < 8; t8 += 3) {          // 16-row tiles of this chunk
        const int tile = pc * 8 + t8;
        const float* xr = x + ((size_t)b * T_LEN + tile * 16 + mrow) * 200;
        bf16x8 afr[7];
#pragma unroll
        for (int s = 0; s < 7; ++s) {
          const int k0 = s * 32 + kg * 8;
          bf16x8 v;
          if (k0 <= 192) {
            float4 a  = *reinterpret_cast<const float4*>(xr + k0);
            float4 b4 = *reinterpret_cast<const float4*>(xr + k0 + 4);
            v[0] = (bf16_t)a.x;  v[1] = (bf16_t)a.y;  v[2] = (bf16_t)a.z;  v[3] = (bf16_t)a.w;
            v[4] = (bf16_t)b4.x; v[5] = (bf16_t)b4.y; v[6] = (bf16_t)b4.z; v[7] = (bf16_t)b4.w;
          } else {
            v[0] = (bf16_t)0.f; v[1] = (bf16_t)0.f; v[2] = (bf16_t)0.f; v[3] = (bf16_t)0.f;
            v[4] = (bf16_t)0.f; v[5] = (bf16_t)0.f; v[6] = (bf16_t)0.f; v[7] = (bf16_t)0.f;
          }
          afr[s] = v;
        }

        f32x4 acc0 = {0.f,0.f,0.f,0.f}, acc1 = {0.f,0.f,0.f,0.f};
        f32x4 acc2 = {0.f,0.f,0.f,0.f}, acc3 = {0.f,0.f,0.f,0.f};
#pragma unroll
        for (int s = 0; s < 7; ++s) {
          acc0 = __builtin_amdgcn_mfma_f32_16x16x32_bf16(afr[s], Bv[0*7+s], acc0, 0,0,0);
          acc1 = __builtin_amdgcn_mfma_f32_16x16x32_bf16(afr[s], Bv[1*7+s], acc1, 0,0,0);
          acc2 = __builtin_amdgcn_mfma_f32_16x16x32_bf16(afr[s], Bv[2*7+s], acc2, 0,0,0);
          acc3 = __builtin_amdgcn_mfma_f32_16x16x32_bf16(afr[s], Bv[3*7+s], acc3, 0,0,0);
        }

        // C/D: col = lane&15, row = (lane>>4)*4 + q.  Stride-68 rows.
        float* dst = xsf[pc & 1] + (t8 * 16) * XSTR;
#pragma unroll
        for (int q = 0; q < 4; ++q) {
          float* rowp = dst + (kg * 4 + q) * XSTR;
          rowp[ 0 + cb] = acc0[q] + bv0;
          rowp[16 + cb] = acc1[q] + bv1;
          rowp[32 + cb] = acc2[q] + bv2;
          rowp[48 + cb] = acc3[q] + bv3;
        }
      }
    };

    produce(0);
    for (int ch = 0; ch <= NCH; ++ch) {   // 9 barriers total
      __syncthreads();
      if (ch + 1 < NCH) produce(ch + 1);
    }
    return;
  }

  // ================= scanner wave (wave 0) =================
  __builtin_amdgcn_s_setprio(1);
  const int g = lane & 3;
  const int j = lane >> 2;
  const int r = (g << 4) | j;

  const float sfac = (g == 2) ? (-2.f * LOG2E) : (-LOG2E);
  const float pfac = (g == 0) ? (2.f * LOG2E) : ((g == 2) ? 2.f : 1.f);
  const float qfac = (g == 2) ? -1.f : 0.f;

  half2_t wpk[8];
#pragma unroll
  for (int q = 0; q < 4; ++q) {
    float4 w = *reinterpret_cast<const float4*>(Whh + r * 16 + q * 4);
    wpk[q * 2 + 0] = __builtin_amdgcn_cvt_pkrtz(w.x * sfac, w.y * sfac);
    wpk[q * 2 + 1] = __builtin_amdgcn_cvt_pkrtz(w.z * sfac, w.w * sfac);
  }

  float c = c0[b * 16 + j] * (2.f * LOG2E);       // scaled cell state
  float hmine = h0[b * 16 + j];                   // quad-uniform
  int hp0, hp1, hp2, hp3, hp4, hp5, hp6, hp7;
  PACKH(hmine, hp0, hp1, hp2, hp3, hp4, hp5, hp6, hp7);

  unsigned short* hq = hst + (size_t)b * (16 * T_LEN) + j * T_LEN;  // [b][j][t]

  __syncthreads();                                // B0: chunk 0 ready

  for (int ch = 0; ch < NCH; ++ch) {
    const float* xc = xsf[ch & 1];
    float buf[8];
#pragma unroll
    for (int u = 0; u < 8; ++u) buf[u] = xc[u * XSTR + lane];

    for (int ts = 0; ts < CHUNK; ts += 8) {
      float hsv[8];
#pragma unroll
      for (int u = 0; u < 8; ++u) {
        const float gin = buf[u];                 // sfac*(Wx+b), f32
        if (ts < CHUNK - 8) buf[u] = xc[(ts + 8 + u) * XSTR + lane];

        // pre = sfac*(gin_raw + Whh h): 2 chains of 4 dot2 + combine
        float d0 = FDOT2(wpk[0], i2h2(hp0), gin);
        d0 = FDOT2(wpk[1], i2h2(hp1), d0);
        d0 = FDOT2(wpk[2], i2h2(hp2), d0);
        d0 = FDOT2(wpk[3], i2h2(hp3), d0);
        float d1 = FDOT2(wpk[4], i2h2(hp4), 0.f);
        d1 = FDOT2(wpk[5], i2h2(hp5), d1);
        d1 = FDOT2(wpk[6], i2h2(hp6), d1);
        d1 = FDOT2(wpk[7], i2h2(hp7), d1);
        float pre = d0 + d1;

        float e = fexp2(pre);
        float z = frcp(1.f + e);
        float y = fmaf(pfac, z, qfac);  // g0: 2log2e*i, g1: f, g2: tanh g, g3: o

        // c' = f*c' + (2log2e*i)*g  via quad DPP combine
        float t1 = DPPF(y, 0x4E) * y;             // lane0: (2log2e*i)*g
        float ig = DPPF(t1, 0x00);                // broadcast to quad
        c = fmaf(DPPF(y, 0x55), c, ig);           // f from lane1

        float e2 = fexp2(c);                      // e^{2c_true}
        float z2 = frcp(1.f + e2);
        float th = fmaf(-2.f, z2, 1.f);           // tanh(c_true)
        float h = DPPF(y, 0xFF) * th;             // o from lane3; quad-uniform

        PACKH(h, hp0, hp1, hp2, hp3, hp4, hp5, hp6, hp7);
        hsv[u] = h;
      }
      if (g == 0) {                               // one 16B store per 8 steps
        uint4 pk;
        pk.x = pkbf(hsv[0], hsv[1]);
        pk.y = pkbf(hsv[2], hsv[3]);
        pk.z = pkbf(hsv[4], hsv[5]);
        pk.w = pkbf(hsv[6], hsv[7]);
        *reinterpret_cast<uint4*>(hq + ch * CHUNK + ts) = pk;
      }
    }

    __syncthreads();                              // B(ch+1): release buf, next ready
  }
}

// ---------------- Kernel 3: head + mean (hst layout [b][j][t]) ----------------
__global__ __launch_bounds__(256) void k3_head(
    const unsigned short* __restrict__ hst,
    const float* __restrict__ W1, const float* __restrict__ b1,
    const float* __restrict__ W2, const float* __restrict__ b2,
    float* __restrict__ out)
{
  __shared__ float ws1[256];
  __shared__ float wsb1[16], wsw2[16];
  __shared__ float red[256];
  const int tid = threadIdx.x;
  const int b = blockIdx.x;

  ws1[tid] = W1[tid];
  if (tid < 16) { wsb1[tid] = b1[tid]; wsw2[tid] = W2[tid]; }
  __syncthreads();
  const float b2s = b2[0];

  const unsigned short* hb = hst + (size_t)b * (16 * T_LEN);
  float acc = 0.f;
#pragma unroll
  for (int it = 0; it < 2; ++it) {
    const int t2 = it * 256 + tid;               // pair index, t = 2*t2
    unsigned int hp[16];
#pragma unroll
    for (int jj = 0; jj < 16; ++jj)
      hp[jj] = *reinterpret_cast<const unsigned int*>(hb + jj * T_LEN + 2 * t2);
    float h0v[16], h1v[16];
#pragma unroll
    for (int k = 0; k < 16; ++k) {
      h0v[k] = bf2f((unsigned short)(hp[k] & 0xffff));
      h1v[k] = bf2f((unsigned short)(hp[k] >> 16));
    }
    float s0 = b2s, s1 = b2s;
#pragma unroll
    for (int jj = 0; jj < 16; ++jj) {
      float p0 = wsb1[jj], p1 = wsb1[jj];
#pragma unroll
      for (int k = 0; k < 16; ++k) {
        const float wv = ws1[jj * 16 + k];
        p0 = fmaf(wv, h0v[k], p0);
        p1 = fmaf(wv, h1v[k], p1);
      }
      p0 = fmaxf(p0, 0.f);
      p1 = fmaxf(p1, 0.f);
      s0 = fmaf(wsw2[jj], p0, s0);
      s1 = fmaf(wsw2[jj], p1, s1);
    }
    acc += frcp(1.f + fexp2(-LOG2E * s0));
    acc += frcp(1.f + fexp2(-LOG2E * s1));
  }

  red[tid] = acc;
  __syncthreads();
  if (tid < 128) red[tid] += red[tid + 128];
  __syncthreads();
  if (tid < 64) {
    float v = red[tid] + red[tid + 64];
    v += __shfl_xor(v, 32, 64);
    v += __shfl_xor(v, 16, 64);
    v += __shfl_xor(v, 8, 64);
    v += __shfl_xor(v, 4, 64);
    v += __shfl_xor(v, 2, 64);
    v += __shfl_xor(v, 1, 64);
    if (tid == 0) out[b] = v * (1.f / T_LEN);
  }
}

// ---------------- launcher ----------------
extern "C" void kernel_launch(void* const* d_in, const int* in_sizes, int n_in,
                              void* d_out, int out_size, void* d_ws, size_t ws_size,
                              hipStream_t stream) {
  const float* x   = (const float*)d_in[0];
  const float* h0  = (const float*)d_in[1];
  const float* c0  = (const float*)d_in[2];
  const float* Wih = (const float*)d_in[3];
  const float* Whh = (const float*)d_in[4];
  const float* bih = (const float*)d_in[5];
  const float* bhh = (const float*)d_in[6];
  const float* W1  = (const float*)d_in[7];
  const float* b1  = (const float*)d_in[8];
  const float* W2  = (const float*)d_in[9];
  const float* b2  = (const float*)d_in[10];

  char* wsb = (char*)d_ws;
  unsigned short* hst = (unsigned short*)wsb;                 // 8 MiB
  bf16x8* wB          = (bf16x8*)(wsb + 8388608);             // 28 KiB
  float* biasPerm     = (float*)(wsb + 8388608 + 32768);      // 256 B

  hipLaunchKernelGGL(k0_prep, dim3(7), dim3(256), 0, stream,
                     Wih, bih, bhh, wB, biasPerm);
  hipLaunchKernelGGL(mega, dim3(NB), dim3(256), 0, stream,
                     x, wB, biasPerm, h0, c0, Whh, hst);
  hipLaunchKernelGGL(k3_head, dim3(NB), dim3(256), 0, stream,
                     hst, W1, b1, W2, b2, (float*)d_out);
}